// Round 12
// baseline (511.460 us; speedup 1.0000x reference)
//
#include <hip/hip_runtime.h>
#include <hip/hip_bf16.h>

#define BATCH 8
#define CH 256
#define HWSZ 4096
#define NGROUPS 8
#define CPG 32
#define GSIZE (CPG * HWSZ)  // 131072 elements per (b, group)

typedef unsigned short u16;
typedef unsigned int u32;
typedef short bf16x8 __attribute__((ext_vector_type(8)));   // 8 bf16 in 4 VGPRs
typedef float f32x4 __attribute__((ext_vector_type(4)));
typedef float f32x16 __attribute__((ext_vector_type(16)));
typedef unsigned int u32x4 __attribute__((ext_vector_type(4)));

union Frag8 {
    bf16x8 v;
    u32x4 q;
    u16 s[8];
};

static __device__ inline u16 f2bf(float f) {
    unsigned int u = __float_as_uint(f);
    u = u + 0x7fffu + ((u >> 16) & 1u);   // round-to-nearest-even
    return (u16)(u >> 16);
}

static __device__ inline u32 pk2bf(float a, float b) {
    __hip_bfloat162 h2 = __float22bfloat162_rn(make_float2(a, b));
    u32 r;
    __builtin_memcpy(&r, &h2, 4);
    return r;
}

// ---------------------------------------------------------------- GroupNorm stats
__global__ __launch_bounds__(256) void gn_stats_part_k(const float* __restrict__ x,
                                                       float* __restrict__ partial) {
    int blk = blockIdx.x;            // 512 = 64 (b,g) * 8 chunks
    int bg = blk >> 3, chunk = blk & 7;
    const float4* base = (const float4*)(x + (size_t)bg * GSIZE + (size_t)chunk * (GSIZE / 8));
    float s = 0.f, ss = 0.f;
    for (int i = threadIdx.x; i < GSIZE / 8 / 4; i += 256) {
        float4 v = base[i];
        s += v.x + v.y + v.z + v.w;
        ss += v.x * v.x + v.y * v.y + v.z * v.z + v.w * v.w;
    }
    #pragma unroll
    for (int off = 32; off > 0; off >>= 1) {
        s += __shfl_xor(s, off, 64);
        ss += __shfl_xor(ss, off, 64);
    }
    __shared__ float red[8];
    int wid = threadIdx.x >> 6;
    if ((threadIdx.x & 63) == 0) { red[wid * 2] = s; red[wid * 2 + 1] = ss; }
    __syncthreads();
    if (threadIdx.x == 0) {
        float S = red[0] + red[2] + red[4] + red[6];
        float SS = red[1] + red[3] + red[5] + red[7];
        atomicAdd(&partial[bg * 2], S);
        atomicAdd(&partial[bg * 2 + 1], SS);
    }
}

__global__ void gn_finalize_k(const float* __restrict__ partial, float* __restrict__ stats) {
    int bg = threadIdx.x;  // 64
    float S = partial[bg * 2], SS = partial[bg * 2 + 1];
    float mean = S / (float)GSIZE;
    float var = SS / (float)GSIZE - mean * mean;
    stats[bg * 2] = mean;
    stats[bg * 2 + 1] = rsqrtf(var + 1e-5f);
}

// ---------------------------------------------------------------- GroupNorm apply
#define TPAD 258
__global__ __launch_bounds__(256) void gn_apply_k(const float* __restrict__ x,
                                                  const float* __restrict__ stats,
                                                  const float* __restrict__ gw,
                                                  const float* __restrict__ gb,
                                                  float* __restrict__ xnf,
                                                  u16* __restrict__ xnt) {
    int b = blockIdx.x >> 6;
    int hw0 = (blockIdx.x & 63) * 64;
    __shared__ u16 lds[64 * TPAD];
    __shared__ float sw[CH], sb[CH], smean[NGROUPS], srstd[NGROUPS];
    if (threadIdx.x < CH) { sw[threadIdx.x] = gw[threadIdx.x]; sb[threadIdx.x] = gb[threadIdx.x]; }
    if (threadIdx.x < NGROUPS) {
        smean[threadIdx.x] = stats[(b * NGROUPS + threadIdx.x) * 2];
        srstd[threadIdx.x] = stats[(b * NGROUPS + threadIdx.x) * 2 + 1];
    }
    __syncthreads();
    for (int it = 0; it < 64; ++it) {
        int idx = it * 256 + threadIdx.x;
        int c = idx >> 6, hwl = idx & 63;
        size_t g = ((size_t)b * CH + c) * HWSZ + hw0 + hwl;
        float v = x[g];
        int grp = c >> 5;
        float xn = (v - smean[grp]) * srstd[grp] * sw[c] + sb[c];
        xnf[g] = xn;
        lds[hwl * TPAD + c] = f2bf(xn);
    }
    __syncthreads();
    int hwl = threadIdx.x >> 2, cb = (threadIdx.x & 3) * 64;
    u16* dst = xnt + ((size_t)b * HWSZ + hw0 + hwl) * CH + cb;
    for (int j = 0; j < 64; j += 8) {
        u16 tmp[8];
        #pragma unroll
        for (int k = 0; k < 8; ++k) tmp[k] = lds[hwl * TPAD + cb + j + k];
        *(u32x4*)(dst + j) = *(u32x4*)tmp;
    }
}

// ---------------------------------------------------------------- QKV GEMM
// Q is pre-scaled by 1/16 (folded attention scale).
__global__ __launch_bounds__(256) void qkv_gemm_k(const float* __restrict__ w,
                                                  const float* __restrict__ bias,
                                                  const u16* __restrict__ xnt,
                                                  u16* __restrict__ qws,
                                                  u16* __restrict__ kws,
                                                  u16* __restrict__ vws) {
    int b = blockIdx.z;
    int o0 = blockIdx.y * 64;
    int n0 = blockIdx.x * 64;
    int w_id = threadIdx.x >> 6;
    int lane = threadIdx.x & 63;
    int jr = lane & 15, g = lane >> 4;
    int orow = o0 + w_id * 16 + jr;
    f32x4 acc[4] = {};
    for (int kk = 0; kk < 8; ++kk) {
        const float* ap = w + (size_t)orow * CH + kk * 32 + g * 8;
        Frag8 af;
        #pragma unroll
        for (int e = 0; e < 8; ++e) af.s[e] = f2bf(ap[e]);
        #pragma unroll
        for (int s = 0; s < 4; ++s) {
            const u16* bp = xnt + ((size_t)b * HWSZ + n0 + s * 16 + jr) * CH + kk * 32 + g * 8;
            Frag8 bfr; bfr.q = *(const u32x4*)bp;
            acc[s] = __builtin_amdgcn_mfma_f32_16x16x32_bf16(af.v, bfr.v, acc[s], 0, 0, 0);
        }
    }
    #pragma unroll
    for (int s = 0; s < 4; ++s) {
        #pragma unroll
        for (int r = 0; r < 4; ++r) {
            int o = o0 + w_id * 16 + g * 4 + r;
            int n = n0 + s * 16 + jr;
            float val = acc[s][r] + bias[o];
            if (o < 256)       qws[((size_t)b * HWSZ + n) * CH + o] = f2bf(val * 0.0625f);
            else if (o < 512)  kws[((size_t)b * HWSZ + n) * CH + (o - 256)] = f2bf(val);
            else               vws[((size_t)b * CH + (o - 512)) * HWSZ + n] = f2bf(val);
        }
    }
}

// ---------------------------------------------------------------- Flash attention
// 4 waves x 32 q = 128 q per block; 32x32x16 MFMA (2x LDS arithmetic intensity).
// K,V double-buffered LDS (128KB), global_load_lds staging, counted vmcnt.
// Swapped operands: S^T = mfma(K, Q) -> lane holds S[k 32 vals][q=lane&31];
// P kept in-register, redistributed to PV B-frag via cvt_pk + shfl_xor(32).
// O^T = mfma(V, P): acc[8] f32x16 (d = 256 rows, col q).
__global__ __launch_bounds__(256, 1) void attn_k(const u16* __restrict__ qws,
                                                 const u16* __restrict__ kws,
                                                 const u16* __restrict__ vws,
                                                 u16* __restrict__ ows) {
    __shared__ u16 kbuf[2][64 * 256];     // 2 x 32KB, row 512B, XOR swizzle (r&7)<<4
    __shared__ u16 vbuf[2][256 * 64];     // 2 x 32KB, row 128B, XOR swizzle (r&7)<<4

    int b = blockIdx.y;
    int q0 = blockIdx.x * 128;
    int tid = threadIdx.x;
    int w_id = tid >> 6;          // 0..3
    int lane = tid & 63;
    int qcol = lane & 31;         // q column within wave's 32-q tile
    int hi = lane >> 5;           // 0/1: K-dim half

    const char* kgbase = (const char*)(kws + ((size_t)b * HWSZ) * CH);
    const char* vgbase = (const char*)(vws + ((size_t)b * CH) * HWSZ);

    // Q B-frags (pre-scaled 1/16): lane holds col q, ch rows ks*16 + hi*8 .. +8
    Frag8 qf[16];
    const u16* qbase = qws + ((size_t)b * HWSZ + q0 + w_id * 32 + qcol) * CH + hi * 8;
    #pragma unroll
    for (int ks = 0; ks < 16; ++ks) qf[ks].q = *(const u32x4*)(qbase + ks * 16);

    // stage K+V tile kt: 8 K-loads + 8 V-loads per wave (32 instr each over 4 waves)
    auto stage = [&](int bufi, int kt) {
        int k0 = kt * 64;
        char* kd = (char*)&kbuf[bufi][0];
        char* vd = (char*)&vbuf[bufi][0];
        #pragma unroll
        for (int ii = 0; ii < 8; ++ii) {
            int i = w_id * 8 + ii;                 // 1KB each (2 rows x 512B)
            int r = i * 2 + (lane >> 5);
            int bl = (lane & 31) * 16;
            int bs = bl ^ ((r & 7) << 4);
            const char* src = kgbase + ((size_t)(k0 + r)) * 512 + bs;
            __builtin_amdgcn_global_load_lds(
                (const __attribute__((address_space(1))) void*)src,
                (__attribute__((address_space(3))) void*)(kd + i * 1024), 16, 0, 0);
        }
        #pragma unroll
        for (int ii = 0; ii < 8; ++ii) {
            int i = w_id * 8 + ii;                 // 1KB each (8 rows x 128B)
            int r = i * 8 + (lane >> 3);
            int bl = (lane & 7) * 16;
            int bs = bl ^ ((r & 7) << 4);
            const char* src = vgbase + (size_t)r * 8192 + (size_t)k0 * 2 + bs;
            __builtin_amdgcn_global_load_lds(
                (const __attribute__((address_space(1))) void*)src,
                (__attribute__((address_space(3))) void*)(vd + i * 1024), 16, 0, 0);
        }
    };

    float m_run = -1e30f, l_run = 0.f;
    f32x16 acc[8] = {};

    stage(0, 0);
    int bufi = 0;

    for (int kt = 0; kt < 64; ++kt) {
        if (kt + 1 < 64) {
            stage(bufi ^ 1, kt + 1);
            asm volatile("s_waitcnt vmcnt(16)" ::: "memory");  // this tile's 16 landed
        } else {
            asm volatile("s_waitcnt vmcnt(0)" ::: "memory");
        }
        __builtin_amdgcn_s_barrier();

        const char* kb = (const char*)&kbuf[bufi][0];
        const char* vb = (const char*)&vbuf[bufi][0];

        // ---- QK^T swapped: sacc[t] = K_t x Q -> S^T[32k x 32q] per tile t
        f32x16 sacc[2] = {};
        __builtin_amdgcn_s_setprio(1);
        #pragma unroll
        for (int ks = 0; ks < 16; ++ks) {
            #pragma unroll
            for (int t = 0; t < 2; ++t) {
                int r = t * 32 + qcol;             // k row (A-frag row = lane&31)
                int cb = ks * 32 + hi * 16;        // ch byte offset
                Frag8 kf; kf.q = *(const u32x4*)(kb + r * 512 + (cb ^ ((r & 7) << 4)));
                sacc[t] = __builtin_amdgcn_mfma_f32_32x32x16_bf16(kf.v, qf[ks].v, sacc[t], 0, 0, 0);
            }
        }
        __builtin_amdgcn_s_setprio(0);

        // ---- online softmax: lane holds 32 S values for q=qcol (k = t*32 + c+8d+4hi)
        float mx = sacc[0][0];
        #pragma unroll
        for (int t = 0; t < 2; ++t)
            #pragma unroll
            for (int e = 0; e < 16; ++e) mx = fmaxf(mx, sacc[t][e]);
        mx = fmaxf(mx, __shfl_xor(mx, 32, 64));

        if (__any(mx > m_run + 8.f)) {       // defer-max
            float mnew = fmaxf(m_run, mx);
            float alpha = __expf(m_run - mnew);
            #pragma unroll
            for (int dt = 0; dt < 8; ++dt)
                #pragma unroll
                for (int e = 0; e < 16; ++e) acc[dt][e] *= alpha;
            l_run *= alpha;
            m_run = mnew;
        }

        float p_[2][16];
        float rs = 0.f;
        #pragma unroll
        for (int t = 0; t < 2; ++t)
            #pragma unroll
            for (int e = 0; e < 16; ++e) {
                float pv = __expf(sacc[t][e] - m_run);
                p_[t][e] = pv;
                rs += pv;
            }
        rs += __shfl_xor(rs, 32, 64);
        l_run += rs;

        // ---- pack P pairs: pk_[t][d][w] = bf16x2 of k = t*32 + 8d + 4hi + {2w, 2w+1}
        u32 pk_[2][4][2];
        #pragma unroll
        for (int t = 0; t < 2; ++t)
            #pragma unroll
            for (int d = 0; d < 4; ++d) {
                pk_[t][d][0] = pk2bf(p_[t][4 * d + 0], p_[t][4 * d + 1]);
                pk_[t][d][1] = pk2bf(p_[t][4 * d + 2], p_[t][4 * d + 3]);
            }

        // ---- build PV B-frags: frag kstep = P[k = kstep*16 + hi*8 .. +8][q]
        // exchange the missing half with lane^32 (same q, other hi)
        Frag8 pf[4];
        #pragma unroll
        for (int kstep = 0; kstep < 4; ++kstep) {
            const int j0 = 2 * kstep, j1 = 2 * kstep + 1;   // compile-time
            u32 x0a = pk_[j0 >> 2][j0 & 3][0], x0b = pk_[j0 >> 2][j0 & 3][1];
            u32 x1a = pk_[j1 >> 2][j1 & 3][0], x1b = pk_[j1 >> 2][j1 & 3][1];
            u32 s0 = hi ? x0a : x1a;           // what the partner needs
            u32 s1 = hi ? x0b : x1b;
            u32 r0 = __shfl_xor(s0, 32, 64);
            u32 r1 = __shfl_xor(s1, 32, 64);
            u32 a0 = hi ? x1a : x0a;           // own half for this frag
            u32 a1 = hi ? x1b : x0b;
            u32x4 f;
            f[0] = hi ? r0 : a0;
            f[1] = hi ? r1 : a1;
            f[2] = hi ? a0 : r0;
            f[3] = hi ? a1 : r1;
            pf[kstep].q = f;
        }

        // ---- PV swapped: acc[dt] = V_dt x P -> O^T[d 32 rows][q]
        __builtin_amdgcn_s_setprio(1);
        #pragma unroll
        for (int dt = 0; dt < 8; ++dt) {
            #pragma unroll
            for (int kstep = 0; kstep < 4; ++kstep) {
                int rr = dt * 32 + qcol;           // d row
                int cb = kstep * 32 + hi * 16;     // k byte offset
                Frag8 vf; vf.q = *(const u32x4*)(vb + rr * 128 + (cb ^ ((rr & 7) << 4)));
                acc[dt] = __builtin_amdgcn_mfma_f32_32x32x16_bf16(vf.v, pf[kstep].v, acc[dt], 0, 0, 0);
            }
        }
        __builtin_amdgcn_s_setprio(0);

        asm volatile("s_waitcnt lgkmcnt(0)" ::: "memory");
        __builtin_amdgcn_s_barrier();
        bufi ^= 1;
    }

    // epilogue: acc[dt] rows d = dt*32 + (e&3) + 8*(e>>2) + 4*hi, col q = qcol
    float inv_l = 1.0f / l_run;
    int n = q0 + w_id * 32 + qcol;
    u16* obase = ows + ((size_t)b * HWSZ + n) * CH;
    #pragma unroll
    for (int dt = 0; dt < 8; ++dt) {
        #pragma unroll
        for (int rq = 0; rq < 4; ++rq) {
            int cbase = dt * 32 + 8 * rq + 4 * hi;
            u32 w0 = pk2bf(acc[dt][4 * rq + 0] * inv_l, acc[dt][4 * rq + 1] * inv_l);
            u32 w1 = pk2bf(acc[dt][4 * rq + 2] * inv_l, acc[dt][4 * rq + 3] * inv_l);
            *(u32*)&obase[cbase] = w0;
            *(u32*)&obase[cbase + 2] = w1;
        }
    }
}

// ---------------------------------------------------------------- out projection + residual
__global__ __launch_bounds__(256) void proj_k(const float* __restrict__ w,
                                              const float* __restrict__ bias,
                                              const u16* __restrict__ ows,
                                              const float* __restrict__ xnf,
                                              float* __restrict__ out) {
    int b = blockIdx.z;
    int o0 = blockIdx.y * 64;
    int n0 = blockIdx.x * 64;
    int w_id = threadIdx.x >> 6;
    int lane = threadIdx.x & 63;
    int jr = lane & 15, g = lane >> 4;
    int orow = o0 + w_id * 16 + jr;
    f32x4 acc[4] = {};
    for (int kk = 0; kk < 8; ++kk) {
        const float* ap = w + (size_t)orow * CH + kk * 32 + g * 8;
        Frag8 af;
        #pragma unroll
        for (int e = 0; e < 8; ++e) af.s[e] = f2bf(ap[e]);
        #pragma unroll
        for (int s = 0; s < 4; ++s) {
            const u16* bp = ows + ((size_t)b * HWSZ + n0 + s * 16 + jr) * CH + kk * 32 + g * 8;
            Frag8 bfr; bfr.q = *(const u32x4*)bp;
            acc[s] = __builtin_amdgcn_mfma_f32_16x16x32_bf16(af.v, bfr.v, acc[s], 0, 0, 0);
        }
    }
    #pragma unroll
    for (int s = 0; s < 4; ++s) {
        #pragma unroll
        for (int r = 0; r < 4; ++r) {
            int o = o0 + w_id * 16 + g * 4 + r;
            int n = n0 + s * 16 + jr;
            size_t gaddr = ((size_t)b * CH + o) * HWSZ + n;
            out[gaddr] = acc[s][r] + bias[o] + xnf[gaddr];
        }
    }
}

// ---------------------------------------------------------------- launch
extern "C" void kernel_launch(void* const* d_in, const int* in_sizes, int n_in,
                              void* d_out, int out_size, void* d_ws, size_t ws_size,
                              hipStream_t stream) {
    const float* x     = (const float*)d_in[0];
    const float* gn_w  = (const float*)d_in[1];
    const float* gn_b  = (const float*)d_in[2];
    const float* qkv_w = (const float*)d_in[3];
    const float* qkv_b = (const float*)d_in[4];
    const float* out_w = (const float*)d_in[5];
    const float* out_b = (const float*)d_in[6];
    float* out = (float*)d_out;

    char* ws = (char*)d_ws;
    const size_t NB = (size_t)BATCH * HWSZ * CH;  // 8M elements
    float* stats   = (float*)ws;                      // 512B
    float* partial = (float*)(ws + 512);              // 512B
    float* xnf     = (float*)(ws + 1024);             // 32 MB
    size_t off = 1024 + NB * 4;
    u16* xnt = (u16*)(ws + off); off += NB * 2;       // 16 MB each
    u16* qws = (u16*)(ws + off); off += NB * 2;
    u16* kws = (u16*)(ws + off); off += NB * 2;
    u16* vws = (u16*)(ws + off); off += NB * 2;
    u16* ows = (u16*)(ws + off); off += NB * 2;

    hipMemsetAsync(partial, 0, 64 * 2 * sizeof(float), stream);
    gn_stats_part_k<<<dim3(512), dim3(256), 0, stream>>>(x, partial);
    gn_finalize_k<<<dim3(1), dim3(64), 0, stream>>>(partial, stats);
    gn_apply_k<<<dim3(512), dim3(256), 0, stream>>>(x, stats, gn_w, gn_b, xnf, xnt);
    qkv_gemm_k<<<dim3(64, 12, 8), dim3(256), 0, stream>>>(qkv_w, qkv_b, xnt, qws, kws, vws);
    attn_k<<<dim3(32, 8), dim3(256), 0, stream>>>(qws, kws, vws, ows);
    proj_k<<<dim3(64, 4, 8), dim3(256), 0, stream>>>(out_w, out_b, ows, xnf, out);
}